// Round 20
// baseline (648.782 us; speedup 1.0000x reference)
//
#include <hip/hip_runtime.h>
#include <math.h>

#define TS 256
#define BB 1024
#define NQ 8
#define INDIM 128
#define CATDIM 136
#define INV2PI 0.15915494309189535f
#define LOG2E  1.4426950408889634f
#define CHUNK 32

typedef float v2f __attribute__((ext_vector_type(2)));

__device__ __forceinline__ float dpp_xor1(float v) {
    return __int_as_float(__builtin_amdgcn_mov_dpp(__float_as_int(v), 0xB1, 0xF, 0xF, true));
}
__device__ __forceinline__ float dpp_xor2(float v) {
    return __int_as_float(__builtin_amdgcn_mov_dpp(__float_as_int(v), 0x4E, 0xF, 0xF, true));
}
__device__ __forceinline__ float dpp_xor8(float v) {   // row_ror:8 within 16-lane row = lane^8
    return __int_as_float(__builtin_amdgcn_mov_dpp(__float_as_int(v), 0x128, 0xF, 0xF, true));
}
__device__ __forceinline__ float swz4(float v)  {      // ds_swizzle xor 4
    return __int_as_float(__builtin_amdgcn_ds_swizzle(__float_as_int(v), 0x101F));
}
__device__ __forceinline__ float swz16(float v) {      // ds_swizzle xor 16
    return __int_as_float(__builtin_amdgcn_ds_swizzle(__float_as_int(v), 0x401F));
}
__device__ __forceinline__ float swz20(float v) {      // ds_swizzle xor 20
    return __int_as_float(__builtin_amdgcn_ds_swizzle(__float_as_int(v), 0x501F));
}
__device__ __forceinline__ float hw_sin(float x) { float r; asm("v_sin_f32 %0, %1" : "=v"(r) : "v"(x)); return r; }
__device__ __forceinline__ float hw_cos(float x) { float r; asm("v_cos_f32 %0, %1" : "=v"(r) : "v"(x)); return r; }
__device__ __forceinline__ float hw_exp(float x) { float r; asm("v_exp_f32 %0, %1" : "=v"(r) : "v"(x)); return r; }
__device__ __forceinline__ float hw_rcp(float x) { float r; asm("v_rcp_f32 %0, %1" : "=v"(r) : "v"(x)); return r; }
__device__ __forceinline__ v2f mk2(float x, float y) { v2f r; r.x = x; r.y = y; return r; }
__device__ __forceinline__ v2f pk_fma(v2f a, v2f b, v2f c) {
    v2f d; asm("v_pk_fma_f32 %0, %1, %2, %3" : "=v"(d) : "v"(a), "v"(b), "v"(c)); return d;
}

// Per-element consumer step body (verified R15/R19 math), textually duplicated
// for A/B via macro. All names suffixed with X.
#define STEP_EL(xbX, s0hX, s1hX, s2hX, s3hX, s4hX, s5hX, s6hX, s7hX, c_ownX, hvX) \
    {                                                                             \
        v2f hacc = pk_fma(mk2(s0hX, s1hX), whq[0], mk2(xbX, 0.f));                \
        hacc = pk_fma(mk2(s2hX, s3hX), whq[1], hacc);                             \
        hacc = pk_fma(mk2(s4hX, s5hX), whq[2], hacc);                             \
        hacc = pk_fma(mk2(s6hX, s7hX), whq[3], hacc);                             \
        float ang = hacc.x + hacc.y;                                              \
        float sa_own = hw_sin(ang);                                               \
        float ca_own = hw_cos(ang);                                               \
        float sa_0, sa_1, ca_0, ca_1;                                             \
        {                                                                         \
            float p = dpp_xor1(sa_own);                                           \
            sa_0 = l0 ? p : sa_own;  sa_1 = l0 ? sa_own : p;                      \
            p = dpp_xor1(ca_own);                                                 \
            ca_0 = l0 ? p : ca_own;  ca_1 = l0 ? ca_own : p;                      \
        }                                                                         \
        float sa00, sa01, sa10, sa11, ca00, ca01, ca10, ca11;                     \
        {                                                                         \
            float p0 = dpp_xor2(sa_0), p1 = dpp_xor2(sa_1);                       \
            sa00 = l1 ? p0 : sa_0;  sa01 = l1 ? sa_0 : p0;                        \
            sa10 = l1 ? p1 : sa_1;  sa11 = l1 ? sa_1 : p1;                        \
            p0 = dpp_xor2(ca_0); p1 = dpp_xor2(ca_1);                             \
            ca00 = l1 ? p0 : ca_0;  ca01 = l1 ? ca_0 : p0;                        \
            ca10 = l1 ? p1 : ca_1;  ca11 = l1 ? ca_1 : p1;                        \
        }                                                                         \
        float saw[8], caw[8];                                                     \
        {                                                                         \
            float p;                                                              \
            p = dpp_xor8(sa00); saw[0] = l3 ? p : sa00; saw[1] = l3 ? sa00 : p;   \
            p = dpp_xor8(sa01); saw[2] = l3 ? p : sa01; saw[3] = l3 ? sa01 : p;   \
            p = dpp_xor8(sa10); saw[4] = l3 ? p : sa10; saw[5] = l3 ? sa10 : p;   \
            p = dpp_xor8(sa11); saw[6] = l3 ? p : sa11; saw[7] = l3 ? sa11 : p;   \
            p = dpp_xor8(ca00); caw[0] = l3 ? p : ca00; caw[1] = l3 ? ca00 : p;   \
            p = dpp_xor8(ca01); caw[2] = l3 ? p : ca01; caw[3] = l3 ? ca01 : p;   \
            p = dpp_xor8(ca10); caw[4] = l3 ? p : ca10; caw[5] = l3 ? ca10 : p;   \
            p = dpp_xor8(ca11); caw[6] = l3 ? p : ca11; caw[7] = l3 ? ca11 : p;   \
        }                                                                         \
        float kE = 0.f;                                                           \
        float d0, d1, zr, zi;                                                     \
        {                                                                         \
            float AmB = cp0c[0] * caw[0];                                         \
            d0 = Chw[0] * (1.f + AmB);                                            \
            d1 = -(Chw[0] * (1.f - AmB));                                         \
            zr = nSw[0] * (hsp0[0] * caw[0]);                                     \
            zi = nSw[0] * (-0.5f * saw[0]);                                       \
        }                                                                         \
        _Pragma("unroll")                                                         \
        for (int w = 1; w < 8; ++w) {                                             \
            float gr = hsp0[w] * caw[w];                                          \
            float gi = -0.5f * saw[w];                                            \
            float AmB = cp0c[w] * caw[w];                                         \
            float sum = d0 + d1, dif = d0 - d1;                                   \
            float p = gr * zr, qv = gi * zi;                                      \
            float Ew = fmaf(4.f, p, sum);                                         \
            kE = fmaf(sel[w - 1], Ew, kE);                                        \
            float ad = AmB * dif;                                                 \
            float e1 = sum + ad, e3 = sum - ad;                                   \
            float e2 = p - qv, e4 = p + qv;                                       \
            float T0 = fmaf(4.f, e2, e1);                                         \
            float T1 = fmaf(4.f, e4, e3);                                         \
            float f1 = fmaf(gr, sum, zr);                                         \
            float f3 = fmaf(AmB, zi, gi * dif);                                   \
            d0 = Chw[w] * T0;                                                     \
            d1 = -(Chw[w] * T1);                                                  \
            zr = nSw[w] * f1;                                                     \
            zi = nSw[w] * f3;                                                     \
        }                                                                         \
        {                                                                         \
            float E7 = (d0 + d1) + 2.f * zr;                                      \
            kE = fmaf(sel[7], E7, kE);                                            \
        }                                                                         \
        float y = hw_exp(kE);                                                     \
        float a = fmaf(Aa, y, Bb) * hw_rcp(y + 1.f);                              \
        float b4 = swz4(a);                                                       \
        float b16 = swz16(a);                                                     \
        float b20 = swz20(a);                                                     \
        float e0 = g1b ? b16 : a;                                                 \
        float e1s = g1b ? b20 : b4;                                               \
        float e2s = g1b ? a : b16;                                                \
        float e3s = g1b ? b4 : b20;                                               \
        float fv = g0b ? e1s : e0;                                                \
        float iv = g0b ? e0 : e1s;                                                \
        float gv = g0b ? e3s : e2s;                                               \
        float ov = g0b ? e2s : e3s;                                               \
        c_ownX = fmaf(fv, c_ownX, iv * gv);                                       \
        float e2c = hw_exp(c_ownX * (2.f * LOG2E));                               \
        hvX = ov * ((e2c - 1.f) * hw_rcp(e2c + 1.f));                             \
        s0hX = hvX;                                                               \
        s4hX = dpp_xor1(s0hX);                                                    \
        s2hX = dpp_xor2(s0hX);                                                    \
        s6hX = dpp_xor2(s4hX);                                                    \
        s1hX = dpp_xor8(s0hX);                                                    \
        s5hX = dpp_xor8(s4hX);                                                    \
        s3hX = dpp_xor8(s2hX);                                                    \
        s7hX = dpp_xor8(s6hX);                                                    \
    }

// ============ Producer/consumer, 4 elements per block ============
// Block = 128 threads. Wave 0: xproj for 4 elements -> 128 KB LDS, chunked
// CHUNK rows ahead. Wave 1: verified R15 TM-recurrence body x2 elements per
// 32-lane half (A/B ILP, the R12-verified lever). R15 bit layout per half:
// q = 4*l0+2*l1+l3 (DPP masks 1,2,8), g = bits 2,4 (swz 4/16/20), el2 = bit5.
// Both waves execute every barrier (9 total) — no timing assumptions.
__launch_bounds__(128, 1)
__global__ void qlstm_pc4(const float* __restrict__ x,
    const float* __restrict__ Wf, const float* __restrict__ bf, const float* __restrict__ Pf,
    const float* __restrict__ Wi, const float* __restrict__ bi, const float* __restrict__ Pi,
    const float* __restrict__ Wg, const float* __restrict__ bg, const float* __restrict__ Pg,
    const float* __restrict__ Wo, const float* __restrict__ bo, const float* __restrict__ Po,
    float* __restrict__ out, float* __restrict__ hst, float* __restrict__ cst)
{
    const int tid = threadIdx.x;
    const int wv = tid >> 6;
    const int lane = tid & 63;

    __shared__ float xp[4 * TS * 32];          // 128 KB

    const float* Wlist[4] = { Wf, Wi, Wg, Wo };
    const float* blist[4] = { bf, bi, bg, bo };
    const float* Plist[4] = { Pf, Pi, Pg, Po };

    if (wv == 0) {
        // ---------------- producer ----------------
        const int pq = lane >> 3;             // row 0..7
        const int kg = lane & 7;              // 16-col chunk
        float4 wfrag[4][4];
        float bias_w[4];
        #pragma unroll
        for (int g4 = 0; g4 < 4; ++g4) {
            const float* Wr = Wlist[g4] + pq * CATDIM + kg * 16;
            #pragma unroll
            for (int c4 = 0; c4 < 4; ++c4) {
                float4 v = *(const float4*)(Wr + c4 * 4);
                v.x *= INV2PI; v.y *= INV2PI; v.z *= INV2PI; v.w *= INV2PI;
                wfrag[g4][c4] = v;
            }
            bias_w[g4] = blist[g4][pq] * INV2PI;
        }

        auto fill_chunk = [&](int base) {
            #pragma unroll 1
            for (int el = 0; el < 4; ++el) {
                const int b = blockIdx.x * 4 + el;
                for (int tt = 0; tt < CHUNK; ++tt) {
                    const int t = base + tt;
                    const float* xr = x + ((size_t)t * BB + b) * INDIM + kg * 16;
                    float4 x0 = *(const float4*)(xr);
                    float4 x1 = *(const float4*)(xr + 4);
                    float4 x2 = *(const float4*)(xr + 8);
                    float4 x3 = *(const float4*)(xr + 12);
                    #pragma unroll
                    for (int g4 = 0; g4 < 4; ++g4) {
                        float p =
                            x0.x*wfrag[g4][0].x + x0.y*wfrag[g4][0].y + x0.z*wfrag[g4][0].z + x0.w*wfrag[g4][0].w +
                            x1.x*wfrag[g4][1].x + x1.y*wfrag[g4][1].y + x1.z*wfrag[g4][1].z + x1.w*wfrag[g4][1].w +
                            x2.x*wfrag[g4][2].x + x2.y*wfrag[g4][2].y + x2.z*wfrag[g4][2].z + x2.w*wfrag[g4][2].w +
                            x3.x*wfrag[g4][3].x + x3.y*wfrag[g4][3].y + x3.z*wfrag[g4][3].z + x3.w*wfrag[g4][3].w;
                        p += dpp_xor1(p);
                        p += dpp_xor2(p);
                        p += __shfl_xor(p, 4, 64);
                        if (kg == 0) xp[(el * TS + t) * 32 + g4 * 8 + pq] = p + bias_w[g4];
                    }
                }
            }
        };

        fill_chunk(0);
        __syncthreads();
        for (int k = 0; k < TS / CHUNK; ++k) {
            if (k + 1 < TS / CHUNK) fill_chunk((k + 1) * CHUNK);
            __syncthreads();
        }
        // producer holds no output state
    } else {
        // ---------------- consumer: 2 elements per 32-lane half ----------------
        const int l0 = lane & 1, l1 = (lane >> 1) & 1, l3 = (lane >> 3) & 1;
        const int q = 4 * l0 + 2 * l1 + l3;
        const int g = ((lane >> 2) & 1) | ((lane >> 3) & 2);
        const int el2 = lane >> 5;
        const int bA = blockIdx.x * 4 + el2 * 2;
        const int bB = bA + 1;
        const bool g1b = (g & 2) != 0;
        const bool g0b = (g & 1) != 0;

        const float* P = Plist[g];
        float Chw[8], nSw[8], hsp0[8], cp0c[8];
        #pragma unroll
        for (int w = 0; w < 8; ++w) {
            float s1, c1, s0, c0;
            __sincosf(P[8 + w], &s1, &c1);
            __sincosf(P[w], &s0, &c0);
            Chw[w] = 0.5f * c1;
            nSw[w] = -s1;
            hsp0[w] = 0.5f * s0;
            cp0c[w] = c0;
        }
        v2f whq[4];
        {
            const float* Wq = Wlist[g] + q * CATDIM + INDIM;
            #pragma unroll
            for (int p2 = 0; p2 < 4; ++p2)
                whq[p2] = mk2(INV2PI * Wq[q ^ (2 * p2)], INV2PI * Wq[q ^ (2 * p2 + 1)]);
        }
        const float kl = ((g == 2) ? 2.f : -1.f) * LOG2E;
        const float Aa = (g == 2) ? 1.f : 0.f;
        const float Bb = (g == 2) ? -1.f : 1.f;
        float sel[8];
        #pragma unroll
        for (int i = 0; i < 8; ++i) sel[i] = (q == i) ? kl : 0.f;

        float s0hA = 0.f, s1hA = 0.f, s2hA = 0.f, s3hA = 0.f;
        float s4hA = 0.f, s5hA = 0.f, s6hA = 0.f, s7hA = 0.f;
        float s0hB = 0.f, s1hB = 0.f, s2hB = 0.f, s3hB = 0.f;
        float s4hB = 0.f, s5hB = 0.f, s6hB = 0.f, s7hB = 0.f;
        float c_ownA = 0.f, hvA = 0.f, c_ownB = 0.f, hvB = 0.f;

        const bool emit = (lane & 0x14) == 0;
        float* optrA = out + (size_t)bA * NQ + q;
        float* optrB = out + (size_t)bB * NQ + q;
        const int offA = (el2 * 2) * (TS * 32) + g * 8 + q;
        const int offB = offA + TS * 32;

        __syncthreads();
        for (int k = 0; k < TS / CHUNK; ++k) {
            const int tbase = k * CHUNK;
            float xbA = xp[offA + tbase * 32];
            float xbB = xp[offB + tbase * 32];
            for (int tt = 0; tt < CHUNK; ++tt) {
                const int t = tbase + tt;
                // prefetch next step's xb (same chunk only — producer owns k+1)
                float nxA = xbA, nxB = xbB;
                if (tt + 1 < CHUNK) {
                    nxA = xp[offA + (t + 1) * 32];
                    nxB = xp[offB + (t + 1) * 32];
                }

                STEP_EL(xbA, s0hA, s1hA, s2hA, s3hA, s4hA, s5hA, s6hA, s7hA, c_ownA, hvA)
                STEP_EL(xbB, s0hB, s1hB, s2hB, s3hB, s4hB, s5hB, s6hB, s7hB, c_ownB, hvB)

                if (emit) { *optrA = hvA; *optrB = hvB; }
                optrA += (size_t)BB * NQ;
                optrB += (size_t)BB * NQ;

                xbA = nxA; xbB = nxB;
            }
            __syncthreads();
        }

        if (emit) {
            hst[bA * NQ + q] = hvA;
            cst[bA * NQ + q] = c_ownA;
            hst[bB * NQ + q] = hvB;
            cst[bB * NQ + q] = c_ownB;
        }
    }
}

extern "C" void kernel_launch(void* const* d_in, const int* in_sizes, int n_in,
                              void* d_out, int out_size, void* d_ws, size_t ws_size,
                              hipStream_t stream) {
    const float* x  = (const float*)d_in[0];
    const float* Wf = (const float*)d_in[1];
    const float* bf = (const float*)d_in[2];
    const float* Pf = (const float*)d_in[3];
    const float* Wi = (const float*)d_in[4];
    const float* bi = (const float*)d_in[5];
    const float* Pi = (const float*)d_in[6];
    const float* Wg = (const float*)d_in[7];
    const float* bg = (const float*)d_in[8];
    const float* Pg = (const float*)d_in[9];
    const float* Wo = (const float*)d_in[10];
    const float* bo = (const float*)d_in[11];
    const float* Po = (const float*)d_in[12];

    float* out = (float*)d_out;
    float* hst = out + (size_t)TS * BB * NQ;
    float* cst = hst + (size_t)BB * NQ;

    qlstm_pc4<<<BB / 4, 128, 0, stream>>>(x, Wf, bf, Pf, Wi, bi, Pi,
                                          Wg, bg, Pg, Wo, bo, Po,
                                          out, hst, cst);
}

// Round 21
// 229.326 us; speedup vs baseline: 2.8291x; 2.8291x over previous
//
#include <hip/hip_runtime.h>
#include <math.h>

#define TS 256
#define BB 1024
#define NQ 8
#define INDIM 128
#define CATDIM 136
#define INV2PI 0.15915494309189535f
#define LOG2E  1.4426950408889634f

typedef float v2f __attribute__((ext_vector_type(2)));

__device__ __forceinline__ float dpp_xor1(float v) {
    return __int_as_float(__builtin_amdgcn_mov_dpp(__float_as_int(v), 0xB1, 0xF, 0xF, true));
}
__device__ __forceinline__ float dpp_xor2(float v) {
    return __int_as_float(__builtin_amdgcn_mov_dpp(__float_as_int(v), 0x4E, 0xF, 0xF, true));
}
__device__ __forceinline__ float dpp_xor8(float v) {   // row_ror:8 within 16-lane row = lane^8
    return __int_as_float(__builtin_amdgcn_mov_dpp(__float_as_int(v), 0x128, 0xF, 0xF, true));
}
__device__ __forceinline__ float swz4(float v)  {      // ds_swizzle xor 4
    return __int_as_float(__builtin_amdgcn_ds_swizzle(__float_as_int(v), 0x101F));
}
__device__ __forceinline__ float swz16(float v) {      // ds_swizzle xor 16
    return __int_as_float(__builtin_amdgcn_ds_swizzle(__float_as_int(v), 0x401F));
}
__device__ __forceinline__ float swz20(float v) {      // ds_swizzle xor 20
    return __int_as_float(__builtin_amdgcn_ds_swizzle(__float_as_int(v), 0x501F));
}
__device__ __forceinline__ float hw_sin(float x) { float r; asm("v_sin_f32 %0, %1" : "=v"(r) : "v"(x)); return r; }
__device__ __forceinline__ float hw_cos(float x) { float r; asm("v_cos_f32 %0, %1" : "=v"(r) : "v"(x)); return r; }
__device__ __forceinline__ float hw_exp(float x) { float r; asm("v_exp_f32 %0, %1" : "=v"(r) : "v"(x)); return r; }
__device__ __forceinline__ float hw_rcp(float x) { float r; asm("v_rcp_f32 %0, %1" : "=v"(r) : "v"(x)); return r; }
__device__ __forceinline__ v2f mk2(float x, float y) { v2f r; r.x = x; r.y = y; return r; }
__device__ __forceinline__ v2f pk_mul(v2f a, v2f b) {
    v2f d; asm("v_pk_mul_f32 %0, %1, %2" : "=v"(d) : "v"(a), "v"(b)); return d;
}
__device__ __forceinline__ v2f pk_fma(v2f a, v2f b, v2f c) {
    v2f d; asm("v_pk_fma_f32 %0, %1, %2, %3" : "=v"(d) : "v"(a), "v"(b), "v"(c)); return d;
}

// ============ Single fused kernel: x-proj + TM recurrence (R15, best) ============
// lane = el2*32 + g1*16 + l3*8 + g0*4 + l1*2 + l0 ; q = 4*l0 + 2*l1 + l3.
// Per step: 8 partial x-dots over own 16-chunk, DPP butterfly-reduce -> own
// row's x-dot; + bias + own-row h-dot (h slots DPP-allgathered, order folded
// into weights); ONE sincos; wires (sa,ca) gathered in ABSOLUTE order via a
// sorted DPP allgather (7 dpp + 14 sel per value, ZERO DS); verified transfer
// chain; sel-fma own-E; activation; 3-swizzle gate gather; lane-local LSTM.
__launch_bounds__(64, 1)
__global__ void qlstm_f(const float* __restrict__ x,
    const float* __restrict__ Wf, const float* __restrict__ bf, const float* __restrict__ Pf,
    const float* __restrict__ Wi, const float* __restrict__ bi, const float* __restrict__ Pi,
    const float* __restrict__ Wg, const float* __restrict__ bg, const float* __restrict__ Pg,
    const float* __restrict__ Wo, const float* __restrict__ bo, const float* __restrict__ Po,
    float* __restrict__ out, float* __restrict__ hst, float* __restrict__ cst)
{
    const int lane = threadIdx.x;
    const int l0 = lane & 1, l1 = (lane >> 1) & 1, l3 = (lane >> 3) & 1;
    const int q = 4 * l0 + 2 * l1 + l3;
    const int g = ((lane >> 2) & 1) | ((lane >> 3) & 2);
    const int el2 = lane >> 5;
    const int b = blockIdx.x * 2 + el2;

    const float* W; const float* P; const float* bs;
    if (g == 0)      { W = Wf; P = Pf; bs = bf; }
    else if (g == 1) { W = Wi; P = Pi; bs = bi; }
    else if (g == 2) { W = Wg; P = Pg; bs = bg; }
    else             { W = Wo; P = Po; bs = bo; }

    // ---- per-wire trig constants ----
    float Chw[8], nSw[8], hsp0[8], cp0c[8];
    #pragma unroll
    for (int w = 0; w < 8; ++w) {
        float s1, c1, s0, c0;
        __sincosf(P[8 + w], &s1, &c1);
        __sincosf(P[w], &s0, &c0);
        Chw[w] = 0.5f * c1;
        nSw[w] = -s1;
        hsp0[w] = 0.5f * s0;
        cp0c[w] = c0;
    }

    // ---- x-weights: 8 rows x own 16-wide k-chunk (chunk = q), 1/2π-scaled ----
    v2f xw[8][8];
    #pragma unroll
    for (int j = 0; j < 8; ++j) {
        const float* Wj = W + j * CATDIM + 16 * q;
        #pragma unroll
        for (int p2 = 0; p2 < 4; ++p2) {
            float4 v = *(const float4*)(Wj + p2 * 4);
            xw[j][p2*2]   = mk2(INV2PI * v.x, INV2PI * v.y);
            xw[j][p2*2+1] = mk2(INV2PI * v.z, INV2PI * v.w);
        }
    }

    // ---- own-row h-weights, h-butterfly slot order folded (slot o = h[q^o]) ----
    v2f whq[4];
    {
        const float* Wq = W + q * CATDIM + INDIM;
        #pragma unroll
        for (int p2 = 0; p2 < 4; ++p2)
            whq[p2] = mk2(INV2PI * Wq[q ^ (2 * p2)], INV2PI * Wq[q ^ (2 * p2 + 1)]);
    }
    const float bq = INV2PI * bs[q];

    // ---- activation constants; kk*log2e folded into E-select ----
    const float kl = ((g == 2) ? 2.f : -1.f) * LOG2E;
    const float Aa = (g == 2) ? 1.f : 0.f;
    const float Bb = (g == 2) ? -1.f : 1.f;
    float sel[8];
    #pragma unroll
    for (int i = 0; i < 8; ++i) sel[i] = (q == i) ? kl : 0.f;

    // ---- state ----
    float s0h = 0.f, s1h = 0.f, s2h = 0.f, s3h = 0.f;
    float s4h = 0.f, s5h = 0.f, s6h = 0.f, s7h = 0.f;
    float c_own = 0.f, hv = 0.f;

    const float* xptr = x + (size_t)b * INDIM + 16 * q;
    float4 xv0 = *(const float4*)(xptr);
    float4 xv1 = *(const float4*)(xptr + 4);
    float4 xv2 = *(const float4*)(xptr + 8);
    float4 xv3 = *(const float4*)(xptr + 12);
    xptr += (size_t)BB * INDIM;

    for (int t = 0; t < TS; ++t) {
        // ---- 8 partial x-dots over own chunk ----
        v2f xc[8] = { mk2(xv0.x, xv0.y), mk2(xv0.z, xv0.w),
                      mk2(xv1.x, xv1.y), mk2(xv1.z, xv1.w),
                      mk2(xv2.x, xv2.y), mk2(xv2.z, xv2.w),
                      mk2(xv3.x, xv3.y), mk2(xv3.z, xv3.w) };
        float pt[8];
        #pragma unroll
        for (int j = 0; j < 8; ++j) {
            v2f acc = pk_mul(xc[0], xw[j][0]);
            acc = pk_fma(xc[1], xw[j][1], acc);
            acc = pk_fma(xc[2], xw[j][2], acc);
            acc = pk_fma(xc[3], xw[j][3], acc);
            acc = pk_fma(xc[4], xw[j][4], acc);
            acc = pk_fma(xc[5], xw[j][5], acc);
            acc = pk_fma(xc[6], xw[j][6], acc);
            acc = pk_fma(xc[7], xw[j][7], acc);
            pt[j] = acc.x + acc.y;
        }

        // prefetch next x chunk
        {
            float4 xn0 = *(const float4*)(xptr);
            float4 xn1 = *(const float4*)(xptr + 4);
            float4 xn2 = *(const float4*)(xptr + 8);
            float4 xn3 = *(const float4*)(xptr + 12);
            xptr += (t < TS - 2) ? (size_t)BB * INDIM : 0;
            xv0 = xn0; xv1 = xn1; xv2 = xn2; xv3 = xn3;
        }

        // ---- butterfly reduce (masks 1,2,8): lane ends with row q (verified R14) ----
        {
            float s, r;
            s = l0 ? pt[0] : pt[4]; r = dpp_xor1(s); pt[0] = (l0 ? pt[4] : pt[0]) + r;
            s = l0 ? pt[1] : pt[5]; r = dpp_xor1(s); pt[1] = (l0 ? pt[5] : pt[1]) + r;
            s = l0 ? pt[2] : pt[6]; r = dpp_xor1(s); pt[2] = (l0 ? pt[6] : pt[2]) + r;
            s = l0 ? pt[3] : pt[7]; r = dpp_xor1(s); pt[3] = (l0 ? pt[7] : pt[3]) + r;
            s = l1 ? pt[0] : pt[2]; r = dpp_xor2(s); pt[0] = (l1 ? pt[2] : pt[0]) + r;
            s = l1 ? pt[1] : pt[3]; r = dpp_xor2(s); pt[1] = (l1 ? pt[3] : pt[1]) + r;
            s = l3 ? pt[0] : pt[1]; r = dpp_xor8(s); pt[0] = (l3 ? pt[1] : pt[0]) + r;
        }

        // ---- own-row angle: xdot + bias + h-dot ----
        v2f hacc = pk_fma(mk2(s0h, s1h), whq[0], mk2(pt[0] + bq, 0.f));
        hacc = pk_fma(mk2(s2h, s3h), whq[1], hacc);
        hacc = pk_fma(mk2(s4h, s5h), whq[2], hacc);
        hacc = pk_fma(mk2(s6h, s7h), whq[3], hacc);
        float ang = hacc.x + hacc.y;

        // ---- ONE sincos ----
        float sa_own = hw_sin(ang);
        float ca_own = hw_cos(ang);

        // ---- SORTED DPP allgather: slots in ABSOLUTE wire order, zero DS ----
        float sa_0, sa_1, ca_0, ca_1;
        {
            float p = dpp_xor1(sa_own);
            sa_0 = l0 ? p : sa_own;  sa_1 = l0 ? sa_own : p;
            p = dpp_xor1(ca_own);
            ca_0 = l0 ? p : ca_own;  ca_1 = l0 ? ca_own : p;
        }
        float sa00, sa01, sa10, sa11, ca00, ca01, ca10, ca11;
        {
            float p0 = dpp_xor2(sa_0), p1 = dpp_xor2(sa_1);
            sa00 = l1 ? p0 : sa_0;  sa01 = l1 ? sa_0 : p0;
            sa10 = l1 ? p1 : sa_1;  sa11 = l1 ? sa_1 : p1;
            p0 = dpp_xor2(ca_0); p1 = dpp_xor2(ca_1);
            ca00 = l1 ? p0 : ca_0;  ca01 = l1 ? ca_0 : p0;
            ca10 = l1 ? p1 : ca_1;  ca11 = l1 ? ca_1 : p1;
        }
        float saw[8], caw[8];
        {
            float p;
            p = dpp_xor8(sa00); saw[0] = l3 ? p : sa00; saw[1] = l3 ? sa00 : p;
            p = dpp_xor8(sa01); saw[2] = l3 ? p : sa01; saw[3] = l3 ? sa01 : p;
            p = dpp_xor8(sa10); saw[4] = l3 ? p : sa10; saw[5] = l3 ? sa10 : p;
            p = dpp_xor8(sa11); saw[6] = l3 ? p : sa11; saw[7] = l3 ? sa11 : p;
            p = dpp_xor8(ca00); caw[0] = l3 ? p : ca00; caw[1] = l3 ? ca00 : p;
            p = dpp_xor8(ca01); caw[2] = l3 ? p : ca01; caw[3] = l3 ? ca01 : p;
            p = dpp_xor8(ca10); caw[4] = l3 ? p : ca10; caw[5] = l3 ? ca10 : p;
            p = dpp_xor8(ca11); caw[6] = l3 ? p : ca11; caw[7] = l3 ? ca11 : p;
        }

        // ---- serial transfer chain (verified R9-R14), own-E via sel-fma ----
        float kE = 0.f;
        float d0, d1, zr, zi;
        {
            float AmB = cp0c[0] * caw[0];
            d0 = Chw[0] * (1.f + AmB);
            d1 = -(Chw[0] * (1.f - AmB));
            zr = nSw[0] * (hsp0[0] * caw[0]);
            zi = nSw[0] * (-0.5f * saw[0]);
        }
        #pragma unroll
        for (int w = 1; w < 8; ++w) {
            float gr = hsp0[w] * caw[w];
            float gi = -0.5f * saw[w];
            float AmB = cp0c[w] * caw[w];
            float sum = d0 + d1, dif = d0 - d1;
            float p = gr * zr, qv = gi * zi;
            float Ew = fmaf(4.f, p, sum);
            kE = fmaf(sel[w - 1], Ew, kE);
            float ad = AmB * dif;
            float e1 = sum + ad, e3 = sum - ad;
            float e2 = p - qv, e4 = p + qv;
            float T0 = fmaf(4.f, e2, e1);
            float T1 = fmaf(4.f, e4, e3);
            float f1 = fmaf(gr, sum, zr);
            float f3 = fmaf(AmB, zi, gi * dif);
            d0 = Chw[w] * T0;
            d1 = -(Chw[w] * T1);
            zr = nSw[w] * f1;
            zi = nSw[w] * f3;
        }
        {
            float E7 = (d0 + d1) + 2.f * zr;
            kE = fmaf(sel[7], E7, kE);
        }

        // ---- own activation ----
        float y = hw_exp(kE);
        float a = fmaf(Aa, y, Bb) * hw_rcp(y + 1.f);

        // ---- gather 4 gates (swizzle masks 4,16,20 — verified R13/R14) ----
        float b4 = swz4(a);
        float b16 = swz16(a);
        float b20 = swz20(a);
        bool g1b = (g & 2) != 0;
        bool g0b = (g & 1) != 0;
        float e0 = g1b ? b16 : a;
        float e1s = g1b ? b20 : b4;
        float e2s = g1b ? a : b16;
        float e3s = g1b ? b4 : b20;
        float fv = g0b ? e1s : e0;
        float iv = g0b ? e0 : e1s;
        float gv = g0b ? e3s : e2s;
        float ov = g0b ? e2s : e3s;

        // ---- lane-local LSTM ----
        c_own = fmaf(fv, c_own, iv * gv);
        float e2c = hw_exp(c_own * (2.f * LOG2E));
        hv = ov * ((e2c - 1.f) * hw_rcp(e2c + 1.f));

        if ((lane & 0x14) == 0)
            out[((size_t)t * BB + b) * NQ + q] = hv;

        // ---- h allgather butterfly (q^o order; weights pre-folded) ----
        s0h = hv;
        s4h = dpp_xor1(s0h);
        s2h = dpp_xor2(s0h);
        s6h = dpp_xor2(s4h);
        s1h = dpp_xor8(s0h);
        s5h = dpp_xor8(s4h);
        s3h = dpp_xor8(s2h);
        s7h = dpp_xor8(s6h);
    }

    if ((lane & 0x14) == 0) {
        hst[b * NQ + q] = hv;
        cst[b * NQ + q] = c_own;
    }
}

extern "C" void kernel_launch(void* const* d_in, const int* in_sizes, int n_in,
                              void* d_out, int out_size, void* d_ws, size_t ws_size,
                              hipStream_t stream) {
    const float* x  = (const float*)d_in[0];
    const float* Wf = (const float*)d_in[1];
    const float* bf = (const float*)d_in[2];
    const float* Pf = (const float*)d_in[3];
    const float* Wi = (const float*)d_in[4];
    const float* bi = (const float*)d_in[5];
    const float* Pi = (const float*)d_in[6];
    const float* Wg = (const float*)d_in[7];
    const float* bg = (const float*)d_in[8];
    const float* Pg = (const float*)d_in[9];
    const float* Wo = (const float*)d_in[10];
    const float* bo = (const float*)d_in[11];
    const float* Po = (const float*)d_in[12];

    float* out = (float*)d_out;
    float* hst = out + (size_t)TS * BB * NQ;
    float* cst = hst + (size_t)BB * NQ;

    qlstm_f<<<BB / 2, 64, 0, stream>>>(x, Wf, bf, Pf, Wi, bi, Pi,
                                       Wg, bg, Pg, Wo, bo, Po,
                                       out, hst, cst);
}